// Round 4
// baseline (172.544 us; speedup 1.0000x reference)
//
#include <hip/hip_runtime.h>

// LinearAttention fp32 [4,16,4096,64]: out = (Q' (K'^T V)) / (Q'.k_sum + eps), X' = elu(X)+1.
// Pass 1 (kv_partial): register-only outer product, no LDS, no barriers.
//   Block = 4 waves over a 128-row s-chunk; wave w owns d-rows [16w,16w+16);
//   lane tile 2(d) x 8(e). K elu'd once per column; V redundancy L1-absorbed.
//   Each block writes one 64x64+64 partial (no atomics).
// Pass 1b (reduce_partials): fold NPB partials per bh.
// Pass 2 (out_kernel): 4-wave blocks, 128 q-rows; kv staged in LDS once; q elu'd +
//   staged per-wave with XOR-swizzled col-chunks; denom fused as extra accumulator.

#define EPS_LA 1e-6f

constexpr int BH = 64;
constexpr int SEQ = 4096;
constexpr int DIM = 64;
constexpr int KVELEM = DIM * DIM + DIM;  // 4160
constexpr int NPB = 32;                  // partial blocks per bh
constexpr int CH = SEQ / NPB;            // 128 rows per block

__device__ __forceinline__ float elu1(float x) {
    return x > 0.f ? x + 1.f : __expf(x);
}
__device__ __forceinline__ void elu4(float4& v) {
    v.x = elu1(v.x); v.y = elu1(v.y); v.z = elu1(v.z); v.w = elu1(v.w);
}

template<bool ATOMIC>
__global__ __launch_bounds__(256) void kv_partial_kernel(
    const float* __restrict__ K, const float* __restrict__ V,
    float* __restrict__ dst) {
    const int bh = blockIdx.y;
    const int blk = blockIdx.x;                 // 0..NPB-1
    const int wave = threadIdx.x >> 6;
    const int lane = threadIdx.x & 63;
    const int dg = lane >> 3;                   // 0..7
    const int eg = lane & 7;                    // 0..7
    const int drow = wave * 16 + dg * 2;        // lane owns d rows drow, drow+1

    const float* Kp = K + ((size_t)bh * SEQ + (size_t)blk * CH) * DIM + drow;
    const float* Vp = V + ((size_t)bh * SEQ + (size_t)blk * CH) * DIM + eg * 8;

    float acc0[8] = {0.f, 0.f, 0.f, 0.f, 0.f, 0.f, 0.f, 0.f};
    float acc1[8] = {0.f, 0.f, 0.f, 0.f, 0.f, 0.f, 0.f, 0.f};
    float cs0 = 0.f, cs1 = 0.f;

    float2 kA = *(const float2*)Kp;
    float4 vA0 = *(const float4*)Vp;
    float4 vA1 = *(const float4*)(Vp + 4);

    for (int s = 0; s < CH; s += 2) {
        // load row s+1 (always in range: s <= CH-2)
        const float2 kB  = *(const float2*)(Kp + (size_t)(s + 1) * DIM);
        const float4 vB0 = *(const float4*)(Vp + (size_t)(s + 1) * DIM);
        const float4 vB1 = *(const float4*)(Vp + (size_t)(s + 1) * DIM + 4);

        // compute row s
        {
            const float k0 = elu1(kA.x), k1 = elu1(kA.y);
            cs0 += k0; cs1 += k1;
            acc0[0] += k0 * vA0.x; acc0[1] += k0 * vA0.y;
            acc0[2] += k0 * vA0.z; acc0[3] += k0 * vA0.w;
            acc0[4] += k0 * vA1.x; acc0[5] += k0 * vA1.y;
            acc0[6] += k0 * vA1.z; acc0[7] += k0 * vA1.w;
            acc1[0] += k1 * vA0.x; acc1[1] += k1 * vA0.y;
            acc1[2] += k1 * vA0.z; acc1[3] += k1 * vA0.w;
            acc1[4] += k1 * vA1.x; acc1[5] += k1 * vA1.y;
            acc1[6] += k1 * vA1.z; acc1[7] += k1 * vA1.w;
        }

        // prefetch row s+2
        if (s + 2 < CH) {
            kA  = *(const float2*)(Kp + (size_t)(s + 2) * DIM);
            vA0 = *(const float4*)(Vp + (size_t)(s + 2) * DIM);
            vA1 = *(const float4*)(Vp + (size_t)(s + 2) * DIM + 4);
        }

        // compute row s+1
        {
            const float k0 = elu1(kB.x), k1 = elu1(kB.y);
            cs0 += k0; cs1 += k1;
            acc0[0] += k0 * vB0.x; acc0[1] += k0 * vB0.y;
            acc0[2] += k0 * vB0.z; acc0[3] += k0 * vB0.w;
            acc0[4] += k0 * vB1.x; acc0[5] += k0 * vB1.y;
            acc0[6] += k0 * vB1.z; acc0[7] += k0 * vB1.w;
            acc1[0] += k1 * vB0.x; acc1[1] += k1 * vB0.y;
            acc1[2] += k1 * vB0.z; acc1[3] += k1 * vB0.w;
            acc1[4] += k1 * vB1.x; acc1[5] += k1 * vB1.y;
            acc1[6] += k1 * vB1.z; acc1[7] += k1 * vB1.w;
        }
    }

    if (ATOMIC) {
        float* w = dst + (size_t)bh * KVELEM;
        #pragma unroll
        for (int j = 0; j < 8; ++j) {
            atomicAdd(&w[(size_t)drow * DIM + eg * 8 + j], acc0[j]);
            atomicAdd(&w[(size_t)(drow + 1) * DIM + eg * 8 + j], acc1[j]);
        }
        if (eg == 0) {
            atomicAdd(&w[DIM * DIM + drow], cs0);
            atomicAdd(&w[DIM * DIM + drow + 1], cs1);
        }
    } else {
        float* w = dst + ((size_t)blk * BH + bh) * KVELEM;
        float4 o;
        o.x = acc0[0]; o.y = acc0[1]; o.z = acc0[2]; o.w = acc0[3];
        *(float4*)&w[(size_t)drow * DIM + eg * 8] = o;
        o.x = acc0[4]; o.y = acc0[5]; o.z = acc0[6]; o.w = acc0[7];
        *(float4*)&w[(size_t)drow * DIM + eg * 8 + 4] = o;
        o.x = acc1[0]; o.y = acc1[1]; o.z = acc1[2]; o.w = acc1[3];
        *(float4*)&w[(size_t)(drow + 1) * DIM + eg * 8] = o;
        o.x = acc1[4]; o.y = acc1[5]; o.z = acc1[6]; o.w = acc1[7];
        *(float4*)&w[(size_t)(drow + 1) * DIM + eg * 8 + 4] = o;
        if (eg == 0) {
            w[DIM * DIM + drow] = cs0;
            w[DIM * DIM + drow + 1] = cs1;
        }
    }
}

__global__ __launch_bounds__(256) void reduce_partials_kernel(
    const float* __restrict__ partial, float* __restrict__ fin) {
    const int bh = blockIdx.y;
    const int j = blockIdx.x * 256 + threadIdx.x;
    if (j >= KVELEM) return;
    float s = 0.f;
    #pragma unroll
    for (int c = 0; c < NPB; ++c)
        s += partial[((size_t)c * BH + bh) * KVELEM + j];
    fin[(size_t)bh * KVELEM + j] = s;
}

// Pass 2: block = 256 thr (4 waves), 128 q-rows/block (32/wave). Thread tile 4x8.
__global__ __launch_bounds__(256) void out_kernel(
    const float* __restrict__ Q, const float* __restrict__ ws,
    float* __restrict__ out) {
    const int bh = blockIdx.y;
    const int rb = blockIdx.x;  // 128-row block
    const int wave = threadIdx.x >> 6, lane = threadIdx.x & 63;
    const int t = threadIdx.x;
    const int tr = lane >> 3;   // 0..7 -> rows 4tr..4tr+3 (within wave's 32)
    const int tc = lane & 7;    // 0..7 -> cols 8tc..8tc+7

    const float* w = ws + (size_t)bh * KVELEM;
    const float* Qw = Q + ((size_t)bh * SEQ + (size_t)rb * 128 + (size_t)wave * 32) * DIM;
    float* Ow = out + ((size_t)bh * SEQ + (size_t)rb * 128 + (size_t)wave * 32) * DIM;

    __shared__ float kvS[DIM][DIM];    // 16 KB
    __shared__ float ksumS[DIM];
    __shared__ float qS[4][32][DIM];   // 32 KB, per-wave, XOR-swizzled col-chunks

    // cooperative kv load (whole block, 4096 floats)
    #pragma unroll
    for (int i = 0; i < 4; ++i) {
        const int idx = (i * 256 + t) * 4;
        *(float4*)&kvS[idx >> 6][idx & 63] = *(const float4*)(w + idx);
    }
    if (t < DIM) ksumS[t] = w[DIM * DIM + t];

    // per-wave q stage: 32 rows x 64 cols, elu'd; col-chunk cc stored at cc^((row>>2)&7)
    #pragma unroll
    for (int it = 0; it < 8; ++it) {
        const int row = it * 4 + (lane >> 4);   // 0..31
        const int cc = lane & 15;               // col chunk 0..15
        float4 qv = *(const float4*)(Qw + (size_t)row * DIM + cc * 4);
        elu4(qv);
        *(float4*)&qS[wave][row][((cc ^ ((row >> 2) & 7)) & 15) * 4] = qv;
    }
    __syncthreads();

    float acc[4][8] = {{0.f}};
    float accd[4] = {0.f, 0.f, 0.f, 0.f};

    #pragma unroll 2
    for (int dc = 0; dc < 16; ++dc) {  // d-chunks of 4
        float4 qv[4];
        #pragma unroll
        for (int i = 0; i < 4; ++i)
            qv[i] = *(const float4*)&qS[wave][tr * 4 + i][((dc ^ tr) & 15) * 4];
        const float4 ks = *(const float4*)&ksumS[dc * 4];
        #pragma unroll
        for (int dd = 0; dd < 4; ++dd) {
            const int d = dc * 4 + dd;
            const float4 ka = *(const float4*)&kvS[d][tc * 8];
            const float4 kb = *(const float4*)&kvS[d][tc * 8 + 4];
            const float ksd = (&ks.x)[dd];
            #pragma unroll
            for (int i = 0; i < 4; ++i) {
                const float qq = (&qv[i].x)[dd];
                accd[i] += qq * ksd;
                acc[i][0] += qq * ka.x; acc[i][1] += qq * ka.y;
                acc[i][2] += qq * ka.z; acc[i][3] += qq * ka.w;
                acc[i][4] += qq * kb.x; acc[i][5] += qq * kb.y;
                acc[i][6] += qq * kb.z; acc[i][7] += qq * kb.w;
            }
        }
    }

    #pragma unroll
    for (int i = 0; i < 4; ++i) {
        const float inv = 1.f / (accd[i] + EPS_LA);
        float4 o0, o1;
        o0.x = acc[i][0] * inv; o0.y = acc[i][1] * inv;
        o0.z = acc[i][2] * inv; o0.w = acc[i][3] * inv;
        o1.x = acc[i][4] * inv; o1.y = acc[i][5] * inv;
        o1.z = acc[i][6] * inv; o1.w = acc[i][7] * inv;
        float* orow = Ow + (size_t)(tr * 4 + i) * DIM + tc * 8;
        *(float4*)(orow) = o0;
        *(float4*)(orow + 4) = o1;
    }
}

extern "C" void kernel_launch(void* const* d_in, const int* in_sizes, int n_in,
                              void* d_out, int out_size, void* d_ws, size_t ws_size,
                              hipStream_t stream) {
    const float* q = (const float*)d_in[0];
    const float* k = (const float*)d_in[1];
    const float* v = (const float*)d_in[2];
    float* out = (float*)d_out;
    float* ws = (float*)d_ws;

    const size_t partial_elems = (size_t)NPB * BH * KVELEM;
    const size_t need = (partial_elems + (size_t)BH * KVELEM) * sizeof(float);

    dim3 blk(256);
    const float* fin_ptr;
    if (ws_size >= need) {
        float* partial = ws;
        float* fin = ws + partial_elems;
        hipLaunchKernelGGL((kv_partial_kernel<false>), dim3(NPB, BH), blk, 0, stream,
                           k, v, partial);
        hipLaunchKernelGGL(reduce_partials_kernel, dim3((KVELEM + 255) / 256, BH),
                           blk, 0, stream, partial, fin);
        fin_ptr = fin;
    } else {
        float* fin = ws;
        hipMemsetAsync(fin, 0, (size_t)BH * KVELEM * sizeof(float), stream);
        hipLaunchKernelGGL((kv_partial_kernel<true>), dim3(NPB, BH), blk, 0, stream,
                           k, v, fin);
        fin_ptr = fin;
    }
    hipLaunchKernelGGL(out_kernel, dim3(SEQ / 128, BH), blk, 0, stream,
                       q, fin_ptr, out);
}

// Round 5
// 81.163 us; speedup vs baseline: 2.1259x; 2.1259x over previous
//
#include <hip/hip_runtime.h>

// LinearAttention fp32 [4,16,4096,64]: out = (Q' (K'^T V)) / (Q'.k_sum + eps), X' = elu(X)+1.
// Pass 1 (kv_mfma): per (bh, 128-row chunk), stage K',V as bf16 TRANSPOSED in LDS
//   (KT[d][s] / VT[e][s], s-pairs packed in dwords, XOR-swizzled), then
//   mfma_f32_16x16x32_bf16: wave w owns e-cols [16w,16w+16), 4 m-tiles x 4 k-steps.
//   ksum computed in fp32 during staging (LDS reduce). Partials -> ws (no atomics).
// Pass 1b (reduce_partials): fold NPB partials per bh.
// Pass 2 (out_kernel): R4 version (measured ~roofline): 4-wave blocks, 128 q-rows,
//   kv in LDS, q elu'd + XOR-swizzled, denom fused as extra accumulator.

#define EPS_LA 1e-6f

constexpr int BH = 64;
constexpr int SEQ = 4096;
constexpr int DIM = 64;
constexpr int KVELEM = DIM * DIM + DIM;  // 4160
constexpr int NPB = 32;                  // partial blocks per bh
constexpr int SCH = SEQ / NPB;           // 128 s-rows per block

typedef short bf16x8 __attribute__((ext_vector_type(8)));
typedef float f32x4 __attribute__((ext_vector_type(4)));

__device__ __forceinline__ float elu1(float x) {
    return x > 0.f ? x + 1.f : __expf(x);
}
__device__ __forceinline__ void elu4(float4& v) {
    v.x = elu1(v.x); v.y = elu1(v.y); v.z = elu1(v.z); v.w = elu1(v.w);
}

// fp32 -> bf16 (RNE; inputs here are always finite)
__device__ __forceinline__ unsigned int f2bf(float x) {
    unsigned int u = __float_as_uint(x);
    return (u + 0x7fffu + ((u >> 16) & 1u)) >> 16;
}
__device__ __forceinline__ unsigned int pack2bf(float lo, float hi) {
    return f2bf(lo) | (f2bf(hi) << 16);
}

// swizzled dword index into KT/VT: row d (64 rows), s-pair index s2 (0..63).
// XOR on dword bits 2..4 keeps 16B alignment; reads 2-way, writes 4-way conflicts.
__device__ __forceinline__ int swz(int d, int s2) {
    return d * 64 + (s2 ^ (((d >> 1) & 7) << 2));
}

template<bool ATOMIC>
__global__ __launch_bounds__(256) void kv_mfma_kernel(
    const float* __restrict__ K, const float* __restrict__ V,
    float* __restrict__ dst) {
    const int bh = blockIdx.y;
    const int blk = blockIdx.x;
    const int t = threadIdx.x;
    const int w = t >> 6, l = t & 63;

    __shared__ unsigned int KT[64 * 64];  // 16 KB: K'^T bf16, [d][s-pair] swizzled
    __shared__ unsigned int VT[64 * 64];  // 16 KB: V^T  bf16
    __shared__ float csumS[16][64];       // 4 KB: per-rowgroup column sums of K'

    const float* Kb = K + ((size_t)bh * SEQ + (size_t)blk * SCH) * DIM;
    const float* Vb = V + ((size_t)bh * SEQ + (size_t)blk * SCH) * DIM;

    const int rg = t >> 4;        // 0..15 row group
    const int c0 = (t & 15) * 4;  // col base

    // ---- stage: load 8 rows (4 even/odd pairs), elu K, pack bf16 pairs, transpose ----
    float cs0 = 0.f, cs1 = 0.f, cs2 = 0.f, cs3 = 0.f;
    #pragma unroll
    for (int i = 0; i < 4; ++i) {
        const int s0 = 2 * rg + 32 * i;  // even row; covers 0..126
        float4 ka = *(const float4*)(Kb + (size_t)s0 * DIM + c0);
        float4 kb = *(const float4*)(Kb + (size_t)(s0 + 1) * DIM + c0);
        const float4 va = *(const float4*)(Vb + (size_t)s0 * DIM + c0);
        const float4 vb = *(const float4*)(Vb + (size_t)(s0 + 1) * DIM + c0);
        elu4(ka); elu4(kb);
        cs0 += ka.x + kb.x; cs1 += ka.y + kb.y;
        cs2 += ka.z + kb.z; cs3 += ka.w + kb.w;
        const int s2 = s0 >> 1;
        KT[swz(c0 + 0, s2)] = pack2bf(ka.x, kb.x);
        KT[swz(c0 + 1, s2)] = pack2bf(ka.y, kb.y);
        KT[swz(c0 + 2, s2)] = pack2bf(ka.z, kb.z);
        KT[swz(c0 + 3, s2)] = pack2bf(ka.w, kb.w);
        VT[swz(c0 + 0, s2)] = pack2bf(va.x, vb.x);
        VT[swz(c0 + 1, s2)] = pack2bf(va.y, vb.y);
        VT[swz(c0 + 2, s2)] = pack2bf(va.z, vb.z);
        VT[swz(c0 + 3, s2)] = pack2bf(va.w, vb.w);
    }
    *(float4*)&csumS[rg][c0] = make_float4(cs0, cs1, cs2, cs3);
    __syncthreads();

    float* wout = ATOMIC ? dst + (size_t)bh * KVELEM
                         : dst + ((size_t)blk * BH + bh) * KVELEM;

    // ---- ksum (fp32): threads 0..63 fold the 16 row-group partials ----
    if (t < 64) {
        float s = 0.f;
        #pragma unroll
        for (int g = 0; g < 16; ++g) s += csumS[g][t];
        if (ATOMIC) atomicAdd(&wout[DIM * DIM + t], s);
        else        wout[DIM * DIM + t] = s;
    }

    // ---- MFMA: wave w owns e-cols [16w,16w+16); m-tiles over d; K=128 in 4 steps ----
    f32x4 acc[4];
    #pragma unroll
    for (int m = 0; m < 4; ++m)
        #pragma unroll
        for (int r = 0; r < 4; ++r) acc[m][r] = 0.f;

    const int lg = l >> 4;       // k-slice group 0..3
    const int lr = l & 15;       // row/col within tile
    #pragma unroll
    for (int ks = 0; ks < 4; ++ks) {
        const int s2b = 16 * ks + 4 * lg;  // 16B-aligned dword base of k-slice
        const bf16x8 bfrag = *reinterpret_cast<const bf16x8*>(&VT[swz(16 * w + lr, s2b)]);
        #pragma unroll
        for (int m = 0; m < 4; ++m) {
            const bf16x8 afrag = *reinterpret_cast<const bf16x8*>(&KT[swz(16 * m + lr, s2b)]);
            acc[m] = __builtin_amdgcn_mfma_f32_16x16x32_bf16(afrag, bfrag, acc[m], 0, 0, 0);
        }
    }

    // ---- store D: tile m -> rows d=16m+4*lg+r, col e=16w+lr ----
    #pragma unroll
    for (int m = 0; m < 4; ++m) {
        #pragma unroll
        for (int r = 0; r < 4; ++r) {
            const int d = 16 * m + 4 * lg + r;
            const int e = 16 * w + lr;
            if (ATOMIC) atomicAdd(&wout[(size_t)d * DIM + e], acc[m][r]);
            else        wout[(size_t)d * DIM + e] = acc[m][r];
        }
    }
}

__global__ __launch_bounds__(256) void reduce_partials_kernel(
    const float* __restrict__ partial, float* __restrict__ fin) {
    const int bh = blockIdx.y;
    const int j = blockIdx.x * 256 + threadIdx.x;
    if (j >= KVELEM) return;
    float s = 0.f;
    #pragma unroll
    for (int c = 0; c < NPB; ++c)
        s += partial[((size_t)c * BH + bh) * KVELEM + j];
    fin[(size_t)bh * KVELEM + j] = s;
}

// Pass 2: block = 256 thr (4 waves), 128 q-rows/block (32/wave). Thread tile 4x8.
// (R4 version, measured ~23us together with reduce — near roofline.)
__global__ __launch_bounds__(256) void out_kernel(
    const float* __restrict__ Q, const float* __restrict__ ws,
    float* __restrict__ out) {
    const int bh = blockIdx.y;
    const int rb = blockIdx.x;  // 128-row block
    const int wave = threadIdx.x >> 6, lane = threadIdx.x & 63;
    const int t = threadIdx.x;
    const int tr = lane >> 3;   // 0..7 -> rows 4tr..4tr+3 (within wave's 32)
    const int tc = lane & 7;    // 0..7 -> cols 8tc..8tc+7

    const float* w = ws + (size_t)bh * KVELEM;
    const float* Qw = Q + ((size_t)bh * SEQ + (size_t)rb * 128 + (size_t)wave * 32) * DIM;
    float* Ow = out + ((size_t)bh * SEQ + (size_t)rb * 128 + (size_t)wave * 32) * DIM;

    __shared__ float kvS[DIM][DIM];    // 16 KB
    __shared__ float ksumS[DIM];
    __shared__ float qS[4][32][DIM];   // 32 KB, per-wave, XOR-swizzled col-chunks

    // cooperative kv load (whole block, 4096 floats)
    #pragma unroll
    for (int i = 0; i < 4; ++i) {
        const int idx = (i * 256 + t) * 4;
        *(float4*)&kvS[idx >> 6][idx & 63] = *(const float4*)(w + idx);
    }
    if (t < DIM) ksumS[t] = w[DIM * DIM + t];

    // per-wave q stage: 32 rows x 64 cols, elu'd; col-chunk cc stored at cc^((row>>2)&7)
    #pragma unroll
    for (int it = 0; it < 8; ++it) {
        const int row = it * 4 + (lane >> 4);   // 0..31
        const int cc = lane & 15;               // col chunk 0..15
        float4 qv = *(const float4*)(Qw + (size_t)row * DIM + cc * 4);
        elu4(qv);
        *(float4*)&qS[wave][row][((cc ^ ((row >> 2) & 7)) & 15) * 4] = qv;
    }
    __syncthreads();

    float acc[4][8] = {{0.f}};
    float accd[4] = {0.f, 0.f, 0.f, 0.f};

    #pragma unroll 2
    for (int dc = 0; dc < 16; ++dc) {  // d-chunks of 4
        float4 qv[4];
        #pragma unroll
        for (int i = 0; i < 4; ++i)
            qv[i] = *(const float4*)&qS[wave][tr * 4 + i][((dc ^ tr) & 15) * 4];
        const float4 ks = *(const float4*)&ksumS[dc * 4];
        #pragma unroll
        for (int dd = 0; dd < 4; ++dd) {
            const int d = dc * 4 + dd;
            const float4 ka = *(const float4*)&kvS[d][tc * 8];
            const float4 kb = *(const float4*)&kvS[d][tc * 8 + 4];
            const float ksd = (&ks.x)[dd];
            #pragma unroll
            for (int i = 0; i < 4; ++i) {
                const float qq = (&qv[i].x)[dd];
                accd[i] += qq * ksd;
                acc[i][0] += qq * ka.x; acc[i][1] += qq * ka.y;
                acc[i][2] += qq * ka.z; acc[i][3] += qq * ka.w;
                acc[i][4] += qq * kb.x; acc[i][5] += qq * kb.y;
                acc[i][6] += qq * kb.z; acc[i][7] += qq * kb.w;
            }
        }
    }

    #pragma unroll
    for (int i = 0; i < 4; ++i) {
        const float inv = 1.f / (accd[i] + EPS_LA);
        float4 o0, o1;
        o0.x = acc[i][0] * inv; o0.y = acc[i][1] * inv;
        o0.z = acc[i][2] * inv; o0.w = acc[i][3] * inv;
        o1.x = acc[i][4] * inv; o1.y = acc[i][5] * inv;
        o1.z = acc[i][6] * inv; o1.w = acc[i][7] * inv;
        float* orow = Ow + (size_t)(tr * 4 + i) * DIM + tc * 8;
        *(float4*)(orow) = o0;
        *(float4*)(orow + 4) = o1;
    }
}

extern "C" void kernel_launch(void* const* d_in, const int* in_sizes, int n_in,
                              void* d_out, int out_size, void* d_ws, size_t ws_size,
                              hipStream_t stream) {
    const float* q = (const float*)d_in[0];
    const float* k = (const float*)d_in[1];
    const float* v = (const float*)d_in[2];
    float* out = (float*)d_out;
    float* ws = (float*)d_ws;

    const size_t partial_elems = (size_t)NPB * BH * KVELEM;
    const size_t need = (partial_elems + (size_t)BH * KVELEM) * sizeof(float);

    dim3 blk(256);
    const float* fin_ptr;
    if (ws_size >= need) {
        float* partial = ws;
        float* fin = ws + partial_elems;
        hipLaunchKernelGGL((kv_mfma_kernel<false>), dim3(NPB, BH), blk, 0, stream,
                           k, v, partial);
        hipLaunchKernelGGL(reduce_partials_kernel, dim3((KVELEM + 255) / 256, BH),
                           blk, 0, stream, partial, fin);
        fin_ptr = fin;
    } else {
        float* fin = ws;
        hipMemsetAsync(fin, 0, (size_t)BH * KVELEM * sizeof(float), stream);
        hipLaunchKernelGGL((kv_mfma_kernel<true>), dim3(NPB, BH), blk, 0, stream,
                           k, v, fin);
        fin_ptr = fin;
    }
    hipLaunchKernelGGL(out_kernel, dim3(SEQ / 128, BH), blk, 0, stream,
                       q, fin_ptr, out);
}